// Round 2
// baseline (388.792 us; speedup 1.0000x reference)
//
#include <hip/hip_runtime.h>

// Trilinear feature interpolation:
//   out[n,f] = sum_{k=0..7} clamp(coeffs[n,k],0,1) * features[corner_idx[n,k], f]
// N = 1e6 queries, V = 1e6 rows, F = 32 features.
//
// Round 4 change: round-1/2 counters show the kernel sits exactly at the
// L2-miss/EA request-path ceiling: (1024 MB gathers + 64 MB streams +
// 128 MB writes) / 187 us = 6.5 TB/s, the chip's streaming ceiling. MALL
// hit-rate changes can't move time (the saturated path is upstream of
// MALL), which is why NT hints were a no-op. Only reducing REQUEST bytes
// helps. Features are N(0,0.01) -> fp16-safe (expected absmax ~1e-4).
// A per-launch conversion pass writes an fp16 table (64 MB) to the
// workspace; the gather kernel then requests 64 B/row instead of 128 B,
// halving the dominant traffic term. fp32 accumulate; fp32 fallback path
// if the workspace is too small.

constexpr int F = 32;
constexpr int QUERIES_PER_BLOCK = 32;   // 32 queries * 8 threads = 256 threads

typedef float    floatx4 __attribute__((ext_vector_type(4)));
typedef _Float16 halfx8  __attribute__((ext_vector_type(8)));
typedef _Float16 halfx4  __attribute__((ext_vector_type(4)));

// ---------------------------------------------------------------- convert
__global__ __launch_bounds__(256) void SPC_85469849190654_convert(
    const float* __restrict__ features,   // [V*F] fp32
    _Float16*    __restrict__ feat_h,     // [V*F] fp16 (workspace)
    int total)                            // V*F
{
    const int i = (blockIdx.x * 256 + threadIdx.x) * 8;
    if (i < total) {
        const float4 a = *reinterpret_cast<const float4*>(features + i);
        const float4 b = *reinterpret_cast<const float4*>(features + i + 4);
        halfx8 h;
        h[0] = (_Float16)a.x; h[1] = (_Float16)a.y;
        h[2] = (_Float16)a.z; h[3] = (_Float16)a.w;
        h[4] = (_Float16)b.x; h[5] = (_Float16)b.y;
        h[6] = (_Float16)b.z; h[7] = (_Float16)b.w;
        *reinterpret_cast<halfx8*>(feat_h + i) = h;
    }
}

// ---------------------------------------------------------------- main fp16
__global__ __launch_bounds__(256) void SPC_85469849190654_kernel_h(
    const float*    __restrict__ coeffs,      // [N,8]
    const int*      __restrict__ corner_idx,  // [N,8]
    const _Float16* __restrict__ feat_h,      // [V,F] fp16
    float*          __restrict__ out,         // [N,F]
    int N)
{
    __shared__ int   s_idx[256];
    __shared__ float s_c[256];

    const int t  = threadIdx.x;
    const int q0 = blockIdx.x * QUERIES_PER_BLOCK;

    const long long load_pos = (long long)q0 * 8 + t;
    if (load_pos < (long long)N * 8) {
        s_idx[t] = corner_idx[load_pos];
        s_c[t]   = coeffs[load_pos];
    } else {
        s_idx[t] = 0;
        s_c[t]   = 0.0f;
    }
    __syncthreads();

    const int q_local = t >> 3;      // 0..31
    const int g       = t & 7;       // 0..7 (feature group of 4)
    const int n       = q0 + q_local;
    if (n >= N) return;

    const int qbase = q_local << 3;
    const _Float16* fb = feat_h + (g << 2);

    // Phase 1: 8 gathers in flight; 8 lanes x 8 B = one 64 B line per row.
    const halfx4 h0 = *reinterpret_cast<const halfx4*>(fb + (size_t)s_idx[qbase + 0] * F);
    const halfx4 h1 = *reinterpret_cast<const halfx4*>(fb + (size_t)s_idx[qbase + 1] * F);
    const halfx4 h2 = *reinterpret_cast<const halfx4*>(fb + (size_t)s_idx[qbase + 2] * F);
    const halfx4 h3 = *reinterpret_cast<const halfx4*>(fb + (size_t)s_idx[qbase + 3] * F);
    const halfx4 h4 = *reinterpret_cast<const halfx4*>(fb + (size_t)s_idx[qbase + 4] * F);
    const halfx4 h5 = *reinterpret_cast<const halfx4*>(fb + (size_t)s_idx[qbase + 5] * F);
    const halfx4 h6 = *reinterpret_cast<const halfx4*>(fb + (size_t)s_idx[qbase + 6] * F);
    const halfx4 h7 = *reinterpret_cast<const halfx4*>(fb + (size_t)s_idx[qbase + 7] * F);

    // Phase 2: fp32 accumulate; coeffs broadcast from LDS.
    float4 acc = make_float4(0.f, 0.f, 0.f, 0.f);
    #define ACC(HK, K)                                             \
    {                                                              \
        float c = s_c[qbase + K];                                  \
        c = fminf(fmaxf(c, 0.0f), 1.0f);                           \
        acc.x = fmaf(c, (float)HK[0], acc.x);                      \
        acc.y = fmaf(c, (float)HK[1], acc.y);                      \
        acc.z = fmaf(c, (float)HK[2], acc.z);                      \
        acc.w = fmaf(c, (float)HK[3], acc.w);                      \
    }
    ACC(h0, 0) ACC(h1, 1) ACC(h2, 2) ACC(h3, 3)
    ACC(h4, 4) ACC(h5, 5) ACC(h6, 6) ACC(h7, 7)
    #undef ACC

    floatx4 accv = {acc.x, acc.y, acc.z, acc.w};
    __builtin_nontemporal_store(
        accv, reinterpret_cast<floatx4*>(out + (size_t)n * F + (g << 2)));
}

// ---------------------------------------------------------------- fp32 fallback
__global__ __launch_bounds__(256) void SPC_85469849190654_kernel_f32(
    const float* __restrict__ coeffs,
    const int*   __restrict__ corner_idx,
    const float* __restrict__ features,
    float*       __restrict__ out,
    int N)
{
    __shared__ int   s_idx[256];
    __shared__ float s_c[256];

    const int t  = threadIdx.x;
    const int q0 = blockIdx.x * QUERIES_PER_BLOCK;

    const long long load_pos = (long long)q0 * 8 + t;
    if (load_pos < (long long)N * 8) {
        s_idx[t] = corner_idx[load_pos];
        s_c[t]   = coeffs[load_pos];
    } else {
        s_idx[t] = 0;
        s_c[t]   = 0.0f;
    }
    __syncthreads();

    const int q_local = t >> 3;
    const int g       = t & 7;
    const int n       = q0 + q_local;
    if (n >= N) return;

    const int   qbase = q_local << 3;
    const float* fb   = features + (g << 2);

    const float4 f0 = *reinterpret_cast<const float4*>(fb + (size_t)s_idx[qbase + 0] * F);
    const float4 f1 = *reinterpret_cast<const float4*>(fb + (size_t)s_idx[qbase + 1] * F);
    const float4 f2 = *reinterpret_cast<const float4*>(fb + (size_t)s_idx[qbase + 2] * F);
    const float4 f3 = *reinterpret_cast<const float4*>(fb + (size_t)s_idx[qbase + 3] * F);
    const float4 f4 = *reinterpret_cast<const float4*>(fb + (size_t)s_idx[qbase + 4] * F);
    const float4 f5 = *reinterpret_cast<const float4*>(fb + (size_t)s_idx[qbase + 5] * F);
    const float4 f6 = *reinterpret_cast<const float4*>(fb + (size_t)s_idx[qbase + 6] * F);
    const float4 f7 = *reinterpret_cast<const float4*>(fb + (size_t)s_idx[qbase + 7] * F);

    float4 acc = make_float4(0.f, 0.f, 0.f, 0.f);
    #define ACC(FK, K)                                             \
    {                                                              \
        float c = s_c[qbase + K];                                  \
        c = fminf(fmaxf(c, 0.0f), 1.0f);                           \
        acc.x = fmaf(c, FK.x, acc.x);                              \
        acc.y = fmaf(c, FK.y, acc.y);                              \
        acc.z = fmaf(c, FK.z, acc.z);                              \
        acc.w = fmaf(c, FK.w, acc.w);                              \
    }
    ACC(f0, 0) ACC(f1, 1) ACC(f2, 2) ACC(f3, 3)
    ACC(f4, 4) ACC(f5, 5) ACC(f6, 6) ACC(f7, 7)
    #undef ACC

    *reinterpret_cast<float4*>(out + (size_t)n * F + (g << 2)) = acc;
}

extern "C" void kernel_launch(void* const* d_in, const int* in_sizes, int n_in,
                              void* d_out, int out_size, void* d_ws, size_t ws_size,
                              hipStream_t stream) {
    const float* coeffs     = (const float*)d_in[0];   // [N,8] fp32
    const int*   corner_idx = (const int*)d_in[1];     // [N,8] int32
    const float* features   = (const float*)d_in[2];   // [V,32] fp32
    float*       out        = (float*)d_out;           // [N,32] fp32

    const int N     = in_sizes[0] / 8;
    const int VF    = in_sizes[2];                     // V * F elements
    const int blocks = (N + QUERIES_PER_BLOCK - 1) / QUERIES_PER_BLOCK;

    const size_t need = (size_t)VF * sizeof(_Float16);
    if (ws_size >= need) {
        _Float16* feat_h = (_Float16*)d_ws;
        const int conv_blocks = (VF / 8 + 255) / 256;
        SPC_85469849190654_convert<<<conv_blocks, 256, 0, stream>>>(
            features, feat_h, VF);
        SPC_85469849190654_kernel_h<<<blocks, 256, 0, stream>>>(
            coeffs, corner_idx, feat_h, out, N);
    } else {
        SPC_85469849190654_kernel_f32<<<blocks, 256, 0, stream>>>(
            coeffs, corner_idx, features, out, N);
    }
}

// Round 3
// 362.055 us; speedup vs baseline: 1.0738x; 1.0738x over previous
//
#include <hip/hip_runtime.h>

// Trilinear feature interpolation:
//   out[n,f] = sum_{k=0..7} clamp(coeffs[n,k],0,1) * features[corner_idx[n,k], f]
// N = 1e6 queries, V = 1e6 rows, F = 32 features.
//
// Mapping: 256-thread block = 32 queries. Thread t -> (query q = t/8, feature
// group g = t%8, 4 floats). Each (query,corner) gather is one fully-used
// 128 B transaction spread across 8 lanes; 8 gathers in flight per thread.
//
// Round 5: REVERT to the fp32 single-kernel formulation (best measured:
// 362.8 us). Round-4's fp16 experiment proved: (a) the kernel is bound by
// the L2<->fabric random-access path at ~3.5-3.8 TB/s effective; (b) miss
// traffic is 64 B-granule-bound, so halving row size only bought 10% on
// the main kernel; (c) the required per-iteration fp32->fp16 conversion
// (192 MB compulsory traffic, ~26 us) exceeds the 19 us it saves, and the
// workspace is re-poisoned between iterations so it cannot be amortized.
// fp32-direct is therefore the structural optimum: 656 MB EA traffic
// (64 MB streams + 125 MB writes + ~454 MB irreducible gather misses) at
// ~3.5 TB/s = ~187 us/dispatch.

constexpr int F = 32;
constexpr int QUERIES_PER_BLOCK = 32;   // 32 queries * 8 threads = 256 threads

typedef float floatx4 __attribute__((ext_vector_type(4)));

__global__ __launch_bounds__(256) void SPC_85469849190654_kernel(
    const float* __restrict__ coeffs,      // [N,8]
    const int*   __restrict__ corner_idx,  // [N,8]
    const float* __restrict__ features,    // [V,F]
    float*       __restrict__ out,         // [N,F]
    int N)
{
    __shared__ int   s_idx[256];
    __shared__ float s_c[256];

    const int t  = threadIdx.x;
    const int q0 = blockIdx.x * QUERIES_PER_BLOCK;

    // Stage 32 queries' (idx, coeff) pairs: one coalesced 4B load each.
    const long long load_pos = (long long)q0 * 8 + t;
    if (load_pos < (long long)N * 8) {
        s_idx[t] = __builtin_nontemporal_load(corner_idx + load_pos);
        s_c[t]   = __builtin_nontemporal_load(coeffs + load_pos);
    } else {
        s_idx[t] = 0;
        s_c[t]   = 0.0f;
    }
    __syncthreads();

    const int q_local = t >> 3;      // 0..31
    const int g       = t & 7;       // 0..7 (feature group of 4)
    const int n       = q0 + q_local;
    if (n >= N) return;

    const int   qbase = q_local << 3;
    const float* fb   = features + (g << 2);

    // Phase 1: issue all 8 gathers back-to-back (8 loads in flight).
    const float4 f0 = *reinterpret_cast<const float4*>(fb + (size_t)s_idx[qbase + 0] * F);
    const float4 f1 = *reinterpret_cast<const float4*>(fb + (size_t)s_idx[qbase + 1] * F);
    const float4 f2 = *reinterpret_cast<const float4*>(fb + (size_t)s_idx[qbase + 2] * F);
    const float4 f3 = *reinterpret_cast<const float4*>(fb + (size_t)s_idx[qbase + 3] * F);
    const float4 f4 = *reinterpret_cast<const float4*>(fb + (size_t)s_idx[qbase + 4] * F);
    const float4 f5 = *reinterpret_cast<const float4*>(fb + (size_t)s_idx[qbase + 5] * F);
    const float4 f6 = *reinterpret_cast<const float4*>(fb + (size_t)s_idx[qbase + 6] * F);
    const float4 f7 = *reinterpret_cast<const float4*>(fb + (size_t)s_idx[qbase + 7] * F);

    // Phase 2: accumulate; coeffs pulled from LDS (broadcast, conflict-free).
    float4 acc = make_float4(0.f, 0.f, 0.f, 0.f);
    #define ACC(FK, K)                                             \
    {                                                              \
        float c = s_c[qbase + K];                                  \
        c = fminf(fmaxf(c, 0.0f), 1.0f);                           \
        acc.x = fmaf(c, FK.x, acc.x);                              \
        acc.y = fmaf(c, FK.y, acc.y);                              \
        acc.z = fmaf(c, FK.z, acc.z);                              \
        acc.w = fmaf(c, FK.w, acc.w);                              \
    }
    ACC(f0, 0) ACC(f1, 1) ACC(f2, 2) ACC(f3, 3)
    ACC(f4, 4) ACC(f5, 5) ACC(f6, 6) ACC(f7, 7)
    #undef ACC

    // Non-temporal store: write-once output stream.
    floatx4 accv = {acc.x, acc.y, acc.z, acc.w};
    __builtin_nontemporal_store(
        accv, reinterpret_cast<floatx4*>(out + (size_t)n * F + (g << 2)));
}

extern "C" void kernel_launch(void* const* d_in, const int* in_sizes, int n_in,
                              void* d_out, int out_size, void* d_ws, size_t ws_size,
                              hipStream_t stream) {
    const float* coeffs     = (const float*)d_in[0];   // [N,8] fp32
    const int*   corner_idx = (const int*)d_in[1];     // [N,8] int32
    const float* features   = (const float*)d_in[2];   // [V,32] fp32
    float*       out        = (float*)d_out;           // [N,32] fp32

    const int N = in_sizes[0] / 8;
    const int blocks = (N + QUERIES_PER_BLOCK - 1) / QUERIES_PER_BLOCK;

    SPC_85469849190654_kernel<<<blocks, 256, 0, stream>>>(
        coeffs, corner_idx, features, out, N);
}